// Round 1
// baseline (87.015 us; speedup 1.0000x reference)
//
#include <hip/hip_runtime.h>

#define NN 8
#define HH 512
#define WW 512
#define CC 3
#define KK 5
#define PADP 2

__global__ __launch_bounds__(256) void conv_local_kernel(
    const float* __restrict__ in,   // (N,H,W,C)
    const float* __restrict__ wt,   // (N,H,W,K*K)
    float* __restrict__ out)        // (N,H,W,C)
{
    const int gid = blockIdx.x * 256 + threadIdx.x;   // pixel id in [0, N*H*W)
    const int w = gid & (WW - 1);
    const int h = (gid >> 9) & (HH - 1);
    const int n = gid >> 18;

    // --- load the 25 per-pixel weights into registers ---
    const float* wp = wt + (size_t)gid * (KK * KK);
    float wreg[KK * KK];
#pragma unroll
    for (int k = 0; k < KK * KK; ++k) wreg[k] = wp[k];

    // --- 5x5 tap loop, 3 channels accumulated in registers ---
    float acc0 = 0.f, acc1 = 0.f, acc2 = 0.f;
    const float* inp = in + (size_t)n * (HH * WW * CC);
#pragma unroll
    for (int dh = 0; dh < KK; ++dh) {
        const int ih = h + dh - PADP;
        const bool rok = ((unsigned)ih < (unsigned)HH);
#pragma unroll
        for (int dw = 0; dw < KK; ++dw) {
            const int iw = w + dw - PADP;
            const bool ok = rok && ((unsigned)iw < (unsigned)WW);
            const float* p = inp + ((size_t)(ih * WW + iw)) * CC;
            float v0 = ok ? p[0] : 0.f;
            float v1 = ok ? p[1] : 0.f;
            float v2 = ok ? p[2] : 0.f;
            const float wv = wreg[dh * KK + dw];
            acc0 = fmaf(v0, wv, acc0);
            acc1 = fmaf(v1, wv, acc1);
            acc2 = fmaf(v2, wv, acc2);
        }
    }

    float* op = out + (size_t)gid * CC;
    op[0] = acc0;
    op[1] = acc1;
    op[2] = acc2;
}

extern "C" void kernel_launch(void* const* d_in, const int* in_sizes, int n_in,
                              void* d_out, int out_size, void* d_ws, size_t ws_size,
                              hipStream_t stream) {
    const float* in = (const float*)d_in[0];   // (8,512,512,3) f32
    const float* wt = (const float*)d_in[1];   // (8,512,512,25) f32
    float* out = (float*)d_out;                // (8,512,512,3) f32

    const int total_pixels = NN * HH * WW;     // 2,097,152
    const int block = 256;
    const int grid = total_pixels / block;     // 8192
    conv_local_kernel<<<grid, block, 0, stream>>>(in, wt, out);
}